// Round 1
// baseline (1090.214 us; speedup 1.0000x reference)
//
#include <hip/hip_runtime.h>

#define NN 100000
#define NE 1600000
#define FF 128
#define KK 25000
#define NB ((NN + 255) / 256)   // 391 blocks of 256 over nodes

// ---------- helpers ----------
__device__ __forceinline__ unsigned long long topk_key(float s, unsigned i) {
  // score is sigmoid output (>=0) so float bits are monotonic in value.
  // Composite key: high 32 = score bits, low 32 = ~index (tie -> lower index wins).
  return (((unsigned long long)__float_as_uint(s)) << 32) |
         (unsigned long long)(0xFFFFFFFFu - i);
}

// ---------- CSR build ----------
__global__ __launch_bounds__(256) void k_degree(const int* __restrict__ tgt,
                                                int* __restrict__ cnt) {
  int e = blockIdx.x * 256 + threadIdx.x;
  if (e < NE) atomicAdd(&cnt[tgt[e]], 1);
}

__global__ __launch_bounds__(256) void k_blocksum(const int* __restrict__ cnt,
                                                  int* __restrict__ bsum) {
  __shared__ int s[256];
  int i = blockIdx.x * 256 + threadIdx.x;
  s[threadIdx.x] = (i < NN) ? cnt[i] : 0;
  __syncthreads();
  for (int off = 128; off > 0; off >>= 1) {
    if (threadIdx.x < off) s[threadIdx.x] += s[threadIdx.x + off];
    __syncthreads();
  }
  if (threadIdx.x == 0) bsum[blockIdx.x] = s[0];
}

__global__ __launch_bounds__(512) void k_scan_bsum(int* __restrict__ bsum) {
  __shared__ int s[512];
  int t = threadIdx.x;
  int own = (t < NB) ? bsum[t] : 0;
  s[t] = own;
  __syncthreads();
  for (int off = 1; off < 512; off <<= 1) {
    int v = (t >= off) ? s[t - off] : 0;
    __syncthreads();
    s[t] += v;
    __syncthreads();
  }
  if (t < NB) bsum[t] = s[t] - own;  // exclusive
}

__global__ __launch_bounds__(256) void k_scan_final(const int* __restrict__ cnt,
                                                    const int* __restrict__ bsum,
                                                    int* __restrict__ offsets) {
  __shared__ int s[256];
  int i = blockIdx.x * 256 + threadIdx.x;
  int own = (i < NN) ? cnt[i] : 0;
  s[threadIdx.x] = own;
  __syncthreads();
  for (int off = 1; off < 256; off <<= 1) {
    int v = (threadIdx.x >= off) ? s[threadIdx.x - off] : 0;
    __syncthreads();
    s[threadIdx.x] += v;
    __syncthreads();
  }
  if (i < NN) offsets[i] = bsum[blockIdx.x] + s[threadIdx.x] - own;
  if (i == NN - 1) offsets[NN] = bsum[blockIdx.x] + s[threadIdx.x];
}

__global__ __launch_bounds__(256) void k_fill(const int* __restrict__ src,
                                              const int* __restrict__ tgt,
                                              const int* __restrict__ offsets,
                                              int* __restrict__ cursor,
                                              int* __restrict__ csr_src) {
  int e = blockIdx.x * 256 + threadIdx.x;
  if (e < NE) {
    int t = tgt[e];
    int p = atomicAdd(&cursor[t], 1);
    csr_src[offsets[t] + p] = src[e];
  }
}

// ---------- mean aggregation (1 wave per node) ----------
template <bool GATED>
__global__ __launch_bounds__(256) void k_agg(const float* __restrict__ vals,
                                             const int* __restrict__ csr_src,
                                             const int* __restrict__ offsets,
                                             const float* __restrict__ gate,
                                             float* __restrict__ outv) {
  int w = threadIdx.x >> 6;
  int lane = threadIdx.x & 63;
  int node = blockIdx.x * 4 + w;
  if (node >= NN) return;
  int beg = offsets[node];
  int end = offsets[node + 1];
  float ax = 0.f, ay = 0.f;
  for (int e = beg; e < end; ++e) {
    int j = csr_src[e];
    float2 v = *reinterpret_cast<const float2*>(&vals[(size_t)j * FF + lane * 2]);
    if (GATED) {
      float g = gate[j];
      ax = fmaf(v.x, g, ax);
      ay = fmaf(v.y, g, ay);
    } else {
      ax += v.x;
      ay += v.y;
    }
  }
  int deg = end - beg;
  float dv = (float)(deg > 0 ? deg : 1);
  float2 o;
  o.x = ax / dv;
  o.y = ay / dv;
  *reinterpret_cast<float2*>(&outv[(size_t)node * FF + lane * 2]) = o;
}

// ---------- GEMM [NN,128] x [128,128] with fused epilogues ----------
// EPI 0: out = A@W (+ A2@W2) + bias                      (pack, DUAL)
// EPI 1: g = A@W + bias; out = sel ? relu(aux*score) : relu(g)   (diffuse 1)
// EPI 2: g = A@W + bias; out = sel ? aux : g                     (diffuse 2)
template <int EPI, bool DUAL>
__global__ __launch_bounds__(256) void k_gemm(const float* __restrict__ A,
                                              const float* __restrict__ W,
                                              const float* __restrict__ A2,
                                              const float* __restrict__ W2,
                                              const float* __restrict__ bias,
                                              const float* __restrict__ aux,
                                              const float* __restrict__ score,
                                              const float* __restrict__ sel,
                                              float* __restrict__ outv) {
  __shared__ float As[8][FF];
  __shared__ float A2s[DUAL ? 8 : 1][FF];
  int r0 = blockIdx.x * 8;
  for (int t = threadIdx.x; t < 8 * FF; t += 256) {
    int r = t >> 7, c = t & 127;
    As[r][c] = A[(size_t)(r0 + r) * FF + c];
    if (DUAL) A2s[r][c] = A2[(size_t)(r0 + r) * FF + c];
  }
  __syncthreads();
  int f = threadIdx.x & 127;
  int rr = threadIdx.x >> 7;  // 0..1 ; thread handles rows rr, rr+2, rr+4, rr+6
  float acc0 = 0.f, acc1 = 0.f, acc2 = 0.f, acc3 = 0.f;
#pragma unroll 4
  for (int k = 0; k < FF; k += 2) {
    float w0 = W[k * FF + f];
    float w1 = W[(k + 1) * FF + f];
    float2 a0 = *reinterpret_cast<const float2*>(&As[rr + 0][k]);
    float2 a1 = *reinterpret_cast<const float2*>(&As[rr + 2][k]);
    float2 a2 = *reinterpret_cast<const float2*>(&As[rr + 4][k]);
    float2 a3 = *reinterpret_cast<const float2*>(&As[rr + 6][k]);
    acc0 = fmaf(a0.x, w0, acc0); acc0 = fmaf(a0.y, w1, acc0);
    acc1 = fmaf(a1.x, w0, acc1); acc1 = fmaf(a1.y, w1, acc1);
    acc2 = fmaf(a2.x, w0, acc2); acc2 = fmaf(a2.y, w1, acc2);
    acc3 = fmaf(a3.x, w0, acc3); acc3 = fmaf(a3.y, w1, acc3);
    if (DUAL) {
      float v0 = W2[k * FF + f];
      float v1 = W2[(k + 1) * FF + f];
      float2 b0 = *reinterpret_cast<const float2*>(&A2s[rr + 0][k]);
      float2 b1 = *reinterpret_cast<const float2*>(&A2s[rr + 2][k]);
      float2 b2 = *reinterpret_cast<const float2*>(&A2s[rr + 4][k]);
      float2 b3 = *reinterpret_cast<const float2*>(&A2s[rr + 6][k]);
      acc0 = fmaf(b0.x, v0, acc0); acc0 = fmaf(b0.y, v1, acc0);
      acc1 = fmaf(b1.x, v0, acc1); acc1 = fmaf(b1.y, v1, acc1);
      acc2 = fmaf(b2.x, v0, acc2); acc2 = fmaf(b2.y, v1, acc2);
      acc3 = fmaf(b3.x, v0, acc3); acc3 = fmaf(b3.y, v1, acc3);
    }
  }
  float b = bias[f];
  float accs[4] = {acc0, acc1, acc2, acc3};
#pragma unroll
  for (int r = 0; r < 4; ++r) {
    int row = rr + 2 * r;
    int gi = r0 + row;
    float g = accs[r] + b;
    size_t oi = (size_t)gi * FF + f;
    if (EPI == 0) {
      outv[oi] = g;
    } else if (EPI == 1) {
      float se = sel[gi];
      float v = (se != 0.f) ? aux[oi] * score[gi] : g;
      outv[oi] = fmaxf(v, 0.f);
    } else {
      float se = sel[gi];
      outv[oi] = (se != 0.f) ? aux[oi] : g;
    }
  }
}

// ---------- scorer ----------
__global__ __launch_bounds__(256) void k_score(const float* __restrict__ h,
                                               const float* __restrict__ wsc,
                                               const float* __restrict__ bsc,
                                               float* __restrict__ score) {
  int lane = threadIdx.x & 63;
  int w = threadIdx.x >> 6;
  int i = blockIdx.x * 4 + w;
  if (i >= NN) return;
  float2 a = *reinterpret_cast<const float2*>(&h[(size_t)i * FF + lane * 2]);
  float2 ww = *reinterpret_cast<const float2*>(&wsc[lane * 2]);
  float v = a.x * ww.x + a.y * ww.y;
#pragma unroll
  for (int off = 32; off > 0; off >>= 1) v += __shfl_xor(v, off, 64);
  if (lane == 0) {
    float t = v + bsc[0];
    score[i] = 1.0f / (1.0f + expf(-t));
  }
}

// ---------- exact top-K: 8-round radix select on 64-bit composite key ----------
__global__ void k_init_state(unsigned* state) {
  state[0] = 0u;  // prefix hi
  state[1] = 0u;  // prefix lo
  state[2] = KK;  // remaining rank
}

__global__ __launch_bounds__(256) void k_hist(const float* __restrict__ score,
                                              const unsigned* __restrict__ state,
                                              unsigned* __restrict__ hist,
                                              int bits_fixed) {
  __shared__ unsigned lh[256];
  for (int i = threadIdx.x; i < 256; i += 256) lh[i] = 0;
  __syncthreads();
  unsigned long long prefix =
      (((unsigned long long)state[0]) << 32) | (unsigned long long)state[1];
  int i = blockIdx.x * 256 + threadIdx.x;
  if (i < NN) {
    unsigned long long key = topk_key(score[i], (unsigned)i);
    bool ok = (bits_fixed == 0) ? true : (((key ^ prefix) >> (64 - bits_fixed)) == 0ull);
    if (ok) {
      unsigned b = (unsigned)((key >> (56 - bits_fixed)) & 0xFFull);
      atomicAdd(&lh[b], 1u);
    }
  }
  __syncthreads();
  for (int i2 = threadIdx.x; i2 < 256; i2 += 256)
    if (lh[i2]) atomicAdd(&hist[i2], lh[i2]);
}

__global__ __launch_bounds__(256) void k_select_round(unsigned* __restrict__ state,
                                                      unsigned* __restrict__ hist,
                                                      int bits_fixed) {
  __shared__ unsigned h[256];
  int t = threadIdx.x;
  h[t] = hist[t];
  hist[t] = 0;  // ready for next round
  __syncthreads();
  if (t == 0) {
    unsigned rem = state[2];
    unsigned long long prefix =
        (((unsigned long long)state[0]) << 32) | (unsigned long long)state[1];
    unsigned cum = 0;
    int bstar = 0;
    for (int b = 255; b >= 0; --b) {
      unsigned c = h[b];
      if (cum + c >= rem) { bstar = b; break; }
      cum += c;
    }
    rem -= cum;
    prefix |= ((unsigned long long)bstar) << (56 - bits_fixed);
    state[0] = (unsigned)(prefix >> 32);
    state[1] = (unsigned)(prefix & 0xFFFFFFFFull);
    state[2] = rem;
  }
}

__global__ __launch_bounds__(256) void k_mask(const float* __restrict__ score,
                                              const unsigned* __restrict__ state,
                                              float* __restrict__ gate,
                                              float* __restrict__ sel) {
  int i = blockIdx.x * 256 + threadIdx.x;
  if (i >= NN) return;
  unsigned long long T =
      (((unsigned long long)state[0]) << 32) | (unsigned long long)state[1];
  unsigned long long key = topk_key(score[i], (unsigned)i);
  float s = (key >= T) ? 1.0f : 0.0f;
  sel[i] = s;
  gate[i] = s * score[i];
}

// ---------- launch ----------
extern "C" void kernel_launch(void* const* d_in, const int* in_sizes, int n_in,
                              void* d_out, int out_size, void* d_ws, size_t ws_size,
                              hipStream_t stream) {
  const float* x = (const float*)d_in[0];
  const int* src = (const int*)d_in[1];
  const int* tgt = (const int*)d_in[2];
  const float* W_self = (const float*)d_in[3];
  const float* W_neigh = (const float*)d_in[4];
  const float* b_pack = (const float*)d_in[5];
  const float* w_score = (const float*)d_in[6];
  const float* b_score = (const float*)d_in[7];
  const float* W_u1 = (const float*)d_in[8];
  const float* b_u1 = (const float*)d_in[9];
  const float* W_u2 = (const float*)d_in[10];
  const float* b_u2 = (const float*)d_in[11];
  float* out = (float*)d_out;

  char* ws = (char*)d_ws;
  size_t off = 0;
  auto alloc = [&](size_t bytes) -> char* {
    char* p = ws + off;
    off += (bytes + 255) & ~(size_t)255;
    return p;
  };
  int* cnt = (int*)alloc((size_t)NN * 4);
  int* offsets = (int*)alloc((size_t)(NN + 1) * 4);
  int* cursor = (int*)alloc((size_t)NN * 4);
  int* csr = (int*)alloc((size_t)NE * 4);
  float* score = (float*)alloc((size_t)NN * 4);
  float* gate = (float*)alloc((size_t)NN * 4);
  float* sel = (float*)alloc((size_t)NN * 4);
  int* bsum = (int*)alloc(512 * 4);
  unsigned* hist = (unsigned*)alloc(256 * 4);
  unsigned* state = (unsigned*)alloc(64);
  float* bufA = (float*)alloc((size_t)NN * FF * 4);
  float* bufB = out;  // h, then d, live in d_out (element-wise in-place safe)

  hipMemsetAsync(cnt, 0, (size_t)NN * 4, stream);
  hipMemsetAsync(cursor, 0, (size_t)NN * 4, stream);
  hipMemsetAsync(hist, 0, 256 * 4, stream);
  k_init_state<<<1, 1, 0, stream>>>(state);

  // CSR by target
  k_degree<<<(NE + 255) / 256, 256, 0, stream>>>(tgt, cnt);
  k_blocksum<<<NB, 256, 0, stream>>>(cnt, bsum);
  k_scan_bsum<<<1, 512, 0, stream>>>(bsum);
  k_scan_final<<<NB, 256, 0, stream>>>(cnt, bsum, offsets);
  k_fill<<<(NE + 255) / 256, 256, 0, stream>>>(src, tgt, offsets, cursor, csr);

  // compress
  k_agg<false><<<NN / 4, 256, 0, stream>>>(x, csr, offsets, nullptr, bufA);
  k_gemm<0, true><<<NN / 8, 256, 0, stream>>>(bufA, W_neigh, x, W_self, b_pack,
                                              nullptr, nullptr, nullptr, bufB);
  k_score<<<NN / 4, 256, 0, stream>>>(bufB, w_score, b_score, score);

  // exact top-K (radix select, no host sync)
  for (int r = 0; r < 8; ++r) {
    k_hist<<<NB, 256, 0, stream>>>(score, state, hist, 8 * r);
    k_select_round<<<1, 256, 0, stream>>>(state, hist, 8 * r);
  }
  k_mask<<<NB, 256, 0, stream>>>(score, state, gate, sel);

  // decompress: diffusion 1
  k_agg<true><<<NN / 4, 256, 0, stream>>>(bufB, csr, offsets, gate, bufA);
  k_gemm<1, false><<<NN / 8, 256, 0, stream>>>(bufA, W_u1, nullptr, nullptr, b_u1,
                                               bufB, score, sel, bufB);
  // diffusion 2
  k_agg<false><<<NN / 4, 256, 0, stream>>>(bufB, csr, offsets, nullptr, bufA);
  k_gemm<2, false><<<NN / 8, 256, 0, stream>>>(bufA, W_u2, nullptr, nullptr, b_u2,
                                               bufB, nullptr, sel, out);
}

// Round 3
// 890.500 us; speedup vs baseline: 1.2243x; 1.2243x over previous
//
#include <hip/hip_runtime.h>

#define NN 100000
#define NE 1600000
#define FF 128
#define KK 25000
#define NB ((NN + 255) / 256)   // 391 blocks of 256 over nodes

// ---------- bf16 helpers (packed pairs in a uint) ----------
__device__ __forceinline__ unsigned short f2b(float f) {
  unsigned u = __float_as_uint(f);
  u += 0x7FFFu + ((u >> 16) & 1u);  // round-to-nearest-even
  return (unsigned short)(u >> 16);
}
__device__ __forceinline__ unsigned pack2(float lo, float hi) {
  return (unsigned)f2b(lo) | ((unsigned)f2b(hi) << 16);
}

// ---------- top-k key ----------
__device__ __forceinline__ unsigned long long topk_key(float s, unsigned i) {
  // score is sigmoid output (>=0) so float bits are monotonic in value.
  return (((unsigned long long)__float_as_uint(s)) << 32) |
         (unsigned long long)(0xFFFFFFFFu - i);
}

// ---------- CSR build ----------
__global__ __launch_bounds__(256) void k_degree(const int* __restrict__ tgt,
                                                int* __restrict__ cnt) {
  int e = blockIdx.x * 256 + threadIdx.x;
  if (e < NE) atomicAdd(&cnt[tgt[e]], 1);
}

__global__ __launch_bounds__(256) void k_blocksum(const int* __restrict__ cnt,
                                                  int* __restrict__ bsum) {
  __shared__ int s[256];
  int i = blockIdx.x * 256 + threadIdx.x;
  s[threadIdx.x] = (i < NN) ? cnt[i] : 0;
  __syncthreads();
  for (int off = 128; off > 0; off >>= 1) {
    if (threadIdx.x < off) s[threadIdx.x] += s[threadIdx.x + off];
    __syncthreads();
  }
  if (threadIdx.x == 0) bsum[blockIdx.x] = s[0];
}

__global__ __launch_bounds__(512) void k_scan_bsum(int* __restrict__ bsum) {
  __shared__ int s[512];
  int t = threadIdx.x;
  int own = (t < NB) ? bsum[t] : 0;
  s[t] = own;
  __syncthreads();
  for (int off = 1; off < 512; off <<= 1) {
    int v = (t >= off) ? s[t - off] : 0;
    __syncthreads();
    s[t] += v;
    __syncthreads();
  }
  if (t < NB) bsum[t] = s[t] - own;  // exclusive
}

__global__ __launch_bounds__(256) void k_scan_final(const int* __restrict__ cnt,
                                                    const int* __restrict__ bsum,
                                                    int* __restrict__ offsets) {
  __shared__ int s[256];
  int i = blockIdx.x * 256 + threadIdx.x;
  int own = (i < NN) ? cnt[i] : 0;
  s[threadIdx.x] = own;
  __syncthreads();
  for (int off = 1; off < 256; off <<= 1) {
    int v = (threadIdx.x >= off) ? s[threadIdx.x - off] : 0;
    __syncthreads();
    s[threadIdx.x] += v;
    __syncthreads();
  }
  if (i < NN) offsets[i] = bsum[blockIdx.x] + s[threadIdx.x] - own;
  if (i == NN - 1) offsets[NN] = bsum[blockIdx.x] + s[threadIdx.x];
}

__global__ __launch_bounds__(256) void k_fill(const int* __restrict__ src,
                                              const int* __restrict__ tgt,
                                              const int* __restrict__ offsets,
                                              int* __restrict__ cursor,
                                              int* __restrict__ csr_src) {
  int e = blockIdx.x * 256 + threadIdx.x;
  if (e < NE) {
    int t = tgt[e];
    int p = atomicAdd(&cursor[t], 1);
    csr_src[offsets[t] + p] = src[e];
  }
}

// ---------- f32 mean aggregation (1 wave per node), order-preserving unroll x4 ----------
__global__ __launch_bounds__(256) void k_agg(const float* __restrict__ vals,
                                             const int* __restrict__ csr,
                                             const int* __restrict__ offsets,
                                             float* __restrict__ outv) {
  int w = threadIdx.x >> 6;
  int lane = threadIdx.x & 63;
  int node = blockIdx.x * 4 + w;
  if (node >= NN) return;
  int beg = offsets[node];
  int end = offsets[node + 1];
  float ax = 0.f, ay = 0.f;
  int e = beg;
  int e4 = beg + ((end - beg) & ~3);
  for (; e < e4; e += 4) {
    int j0 = csr[e], j1 = csr[e + 1], j2 = csr[e + 2], j3 = csr[e + 3];
    float2 v0 = *reinterpret_cast<const float2*>(&vals[(size_t)j0 * FF + lane * 2]);
    float2 v1 = *reinterpret_cast<const float2*>(&vals[(size_t)j1 * FF + lane * 2]);
    float2 v2 = *reinterpret_cast<const float2*>(&vals[(size_t)j2 * FF + lane * 2]);
    float2 v3 = *reinterpret_cast<const float2*>(&vals[(size_t)j3 * FF + lane * 2]);
    ax += v0.x; ay += v0.y;
    ax += v1.x; ay += v1.y;
    ax += v2.x; ay += v2.y;
    ax += v3.x; ay += v3.y;
  }
  for (; e < end; ++e) {
    int j = csr[e];
    float2 v = *reinterpret_cast<const float2*>(&vals[(size_t)j * FF + lane * 2]);
    ax += v.x; ay += v.y;
  }
  int deg = end - beg;
  float inv = 1.0f / (float)(deg > 0 ? deg : 1);
  float2 o;
  o.x = ax * inv;
  o.y = ay * inv;
  *reinterpret_cast<float2*>(&outv[(size_t)node * FF + lane * 2]) = o;
}

// ---------- bf16 mean aggregation (1 wave per node), order-preserving unroll x4 ----------
template <bool GATED>
__global__ __launch_bounds__(256) void k_agg_bf(const unsigned* __restrict__ vals,
                                                const int* __restrict__ csr,
                                                const int* __restrict__ offsets,
                                                const float* __restrict__ sel,
                                                unsigned* __restrict__ outv) {
  int w = threadIdx.x >> 6;
  int lane = threadIdx.x & 63;
  int node = blockIdx.x * 4 + w;
  if (node >= NN) return;
  int beg = offsets[node];
  int end = offsets[node + 1];
  float ax = 0.f, ay = 0.f;
  int e = beg;
  int e4 = beg + ((end - beg) & ~3);
  for (; e < e4; e += 4) {
    int j0 = csr[e], j1 = csr[e + 1], j2 = csr[e + 2], j3 = csr[e + 3];
    unsigned u0 = (!GATED || sel[j0] != 0.f) ? vals[(size_t)j0 * (FF / 2) + lane] : 0u;
    unsigned u1 = (!GATED || sel[j1] != 0.f) ? vals[(size_t)j1 * (FF / 2) + lane] : 0u;
    unsigned u2 = (!GATED || sel[j2] != 0.f) ? vals[(size_t)j2 * (FF / 2) + lane] : 0u;
    unsigned u3 = (!GATED || sel[j3] != 0.f) ? vals[(size_t)j3 * (FF / 2) + lane] : 0u;
    ax += __uint_as_float(u0 << 16); ay += __uint_as_float(u0 & 0xFFFF0000u);
    ax += __uint_as_float(u1 << 16); ay += __uint_as_float(u1 & 0xFFFF0000u);
    ax += __uint_as_float(u2 << 16); ay += __uint_as_float(u2 & 0xFFFF0000u);
    ax += __uint_as_float(u3 << 16); ay += __uint_as_float(u3 & 0xFFFF0000u);
  }
  for (; e < end; ++e) {
    int j = csr[e];
    unsigned u = (!GATED || sel[j] != 0.f) ? vals[(size_t)j * (FF / 2) + lane] : 0u;
    ax += __uint_as_float(u << 16); ay += __uint_as_float(u & 0xFFFF0000u);
  }
  int deg = end - beg;
  float inv = 1.0f / (float)(deg > 0 ? deg : 1);
  outv[(size_t)node * (FF / 2) + lane] = pack2(ax * inv, ay * inv);
}

// ---------- GEMM [NN,128] x [128,128](f32) with fused epilogues ----------
// EPI 0: out = A@W + A2@W2 + bias                      (pack; A f32, A2 f32)
// EPI 1: g = A@W + bias; v = sel ? aux*score : g; out = relu(v); obf = bf16(out)
// EPI 2: g = A@W + bias; out = sel ? aux : g
template <int EPI, bool DUAL, bool ABF16>
__global__ __launch_bounds__(256) void k_gemm(const void* __restrict__ Araw,
                                              const float* __restrict__ W,
                                              const float* __restrict__ A2,
                                              const float* __restrict__ W2,
                                              const float* __restrict__ bias,
                                              const float* __restrict__ aux,
                                              const float* __restrict__ score,
                                              const float* __restrict__ sel,
                                              float* __restrict__ outv,
                                              unsigned short* __restrict__ obf) {
  __shared__ float As[8][FF];
  __shared__ float A2s[DUAL ? 8 : 1][FF];
  int r0 = blockIdx.x * 8;
  if constexpr (ABF16) {
    const unsigned* A = (const unsigned*)Araw;
    for (int t = threadIdx.x; t < 8 * (FF / 2); t += 256) {
      int r = t >> 6, c = t & 63;
      unsigned u = A[(size_t)(r0 + r) * (FF / 2) + c];
      As[r][2 * c] = __uint_as_float(u << 16);
      As[r][2 * c + 1] = __uint_as_float(u & 0xFFFF0000u);
    }
  } else {
    const float* A = (const float*)Araw;
    for (int t = threadIdx.x; t < 8 * FF; t += 256) {
      int r = t >> 7, c = t & 127;
      As[r][c] = A[(size_t)(r0 + r) * FF + c];
    }
  }
  if (DUAL) {
    for (int t = threadIdx.x; t < 8 * FF; t += 256) {
      int r = t >> 7, c = t & 127;
      A2s[r][c] = A2[(size_t)(r0 + r) * FF + c];
    }
  }
  __syncthreads();
  int f = threadIdx.x & 127;
  int rr = threadIdx.x >> 7;  // thread handles rows rr, rr+2, rr+4, rr+6
  float acc0 = 0.f, acc1 = 0.f, acc2 = 0.f, acc3 = 0.f;
#pragma unroll 4
  for (int k = 0; k < FF; k += 2) {
    float w0 = W[k * FF + f];
    float w1 = W[(k + 1) * FF + f];
    float2 a0 = *reinterpret_cast<const float2*>(&As[rr + 0][k]);
    float2 a1 = *reinterpret_cast<const float2*>(&As[rr + 2][k]);
    float2 a2 = *reinterpret_cast<const float2*>(&As[rr + 4][k]);
    float2 a3 = *reinterpret_cast<const float2*>(&As[rr + 6][k]);
    acc0 = fmaf(a0.x, w0, acc0); acc0 = fmaf(a0.y, w1, acc0);
    acc1 = fmaf(a1.x, w0, acc1); acc1 = fmaf(a1.y, w1, acc1);
    acc2 = fmaf(a2.x, w0, acc2); acc2 = fmaf(a2.y, w1, acc2);
    acc3 = fmaf(a3.x, w0, acc3); acc3 = fmaf(a3.y, w1, acc3);
    if (DUAL) {
      float v0 = W2[k * FF + f];
      float v1 = W2[(k + 1) * FF + f];
      float2 b0 = *reinterpret_cast<const float2*>(&A2s[rr + 0][k]);
      float2 b1 = *reinterpret_cast<const float2*>(&A2s[rr + 2][k]);
      float2 b2 = *reinterpret_cast<const float2*>(&A2s[rr + 4][k]);
      float2 b3 = *reinterpret_cast<const float2*>(&A2s[rr + 6][k]);
      acc0 = fmaf(b0.x, v0, acc0); acc0 = fmaf(b0.y, v1, acc0);
      acc1 = fmaf(b1.x, v0, acc1); acc1 = fmaf(b1.y, v1, acc1);
      acc2 = fmaf(b2.x, v0, acc2); acc2 = fmaf(b2.y, v1, acc2);
      acc3 = fmaf(b3.x, v0, acc3); acc3 = fmaf(b3.y, v1, acc3);
    }
  }
  float b = bias[f];
  float accs[4] = {acc0, acc1, acc2, acc3};
#pragma unroll
  for (int r = 0; r < 4; ++r) {
    int row = rr + 2 * r;
    int gi = r0 + row;
    float g = accs[r] + b;
    size_t oi = (size_t)gi * FF + f;
    if (EPI == 0) {
      outv[oi] = g;
    } else if (EPI == 1) {
      float se = sel[gi];
      float v = (se != 0.f) ? aux[oi] * score[gi] : g;
      v = fmaxf(v, 0.f);
      outv[oi] = v;
      obf[oi] = f2b(v);
    } else {
      float se = sel[gi];
      outv[oi] = (se != 0.f) ? aux[oi] : g;
    }
  }
}

// ---------- scorer ----------
__global__ __launch_bounds__(256) void k_score(const float* __restrict__ h,
                                               const float* __restrict__ wsc,
                                               const float* __restrict__ bsc,
                                               float* __restrict__ score) {
  int lane = threadIdx.x & 63;
  int w = threadIdx.x >> 6;
  int i = blockIdx.x * 4 + w;
  if (i >= NN) return;
  float2 a = *reinterpret_cast<const float2*>(&h[(size_t)i * FF + lane * 2]);
  float2 ww = *reinterpret_cast<const float2*>(&wsc[lane * 2]);
  float v = a.x * ww.x + a.y * ww.y;
#pragma unroll
  for (int off = 32; off > 0; off >>= 1) v += __shfl_xor(v, off, 64);
  if (lane == 0) {
    float t = v + bsc[0];
    score[i] = 1.0f / (1.0f + expf(-t));
  }
}

// ---------- exact top-K: 8-round radix select on 64-bit composite key ----------
__global__ void k_init_state(unsigned* state) {
  state[0] = 0u;  // prefix hi
  state[1] = 0u;  // prefix lo
  state[2] = KK;  // remaining rank
}

__global__ __launch_bounds__(256) void k_hist(const float* __restrict__ score,
                                              const unsigned* __restrict__ state,
                                              unsigned* __restrict__ hist,
                                              int bits_fixed) {
  __shared__ unsigned lh[256];
  for (int i = threadIdx.x; i < 256; i += 256) lh[i] = 0;
  __syncthreads();
  unsigned long long prefix =
      (((unsigned long long)state[0]) << 32) | (unsigned long long)state[1];
  int i = blockIdx.x * 256 + threadIdx.x;
  if (i < NN) {
    unsigned long long key = topk_key(score[i], (unsigned)i);
    bool ok = (bits_fixed == 0) ? true : (((key ^ prefix) >> (64 - bits_fixed)) == 0ull);
    if (ok) {
      unsigned b = (unsigned)((key >> (56 - bits_fixed)) & 0xFFull);
      atomicAdd(&lh[b], 1u);
    }
  }
  __syncthreads();
  for (int i2 = threadIdx.x; i2 < 256; i2 += 256)
    if (lh[i2]) atomicAdd(&hist[i2], lh[i2]);
}

__global__ __launch_bounds__(256) void k_select_round(unsigned* __restrict__ state,
                                                      unsigned* __restrict__ hist,
                                                      int bits_fixed) {
  __shared__ unsigned h[256];
  int t = threadIdx.x;
  h[t] = hist[t];
  hist[t] = 0;  // ready for next round
  __syncthreads();
  if (t == 0) {
    unsigned rem = state[2];
    unsigned long long prefix =
        (((unsigned long long)state[0]) << 32) | (unsigned long long)state[1];
    unsigned cum = 0;
    int bstar = 0;
    for (int b = 255; b >= 0; --b) {
      unsigned c = h[b];
      if (cum + c >= rem) { bstar = b; break; }
      cum += c;
    }
    rem -= cum;
    prefix |= ((unsigned long long)bstar) << (56 - bits_fixed);
    state[0] = (unsigned)(prefix >> 32);
    state[1] = (unsigned)(prefix & 0xFFFFFFFFull);
    state[2] = rem;
  }
}

__global__ __launch_bounds__(256) void k_mask(const float* __restrict__ score,
                                              const unsigned* __restrict__ state,
                                              float* __restrict__ sel) {
  int i = blockIdx.x * 256 + threadIdx.x;
  if (i >= NN) return;
  unsigned long long T =
      (((unsigned long long)state[0]) << 32) | (unsigned long long)state[1];
  unsigned long long key = topk_key(score[i], (unsigned)i);
  sel[i] = (key >= T) ? 1.0f : 0.0f;
}

// ---------- pack gated z rows (selected only) to bf16 ----------
__global__ __launch_bounds__(256) void k_gate_zg(const float* __restrict__ h,
                                                 const float* __restrict__ score,
                                                 const float* __restrict__ sel,
                                                 unsigned* __restrict__ zg) {
  int w = threadIdx.x >> 6;
  int lane = threadIdx.x & 63;
  int node = blockIdx.x * 4 + w;
  if (node >= NN) return;
  if (sel[node] == 0.f) return;
  float s = score[node];
  float2 v = *reinterpret_cast<const float2*>(&h[(size_t)node * FF + lane * 2]);
  zg[(size_t)node * (FF / 2) + lane] = pack2(v.x * s, v.y * s);
}

// ---------- launch ----------
extern "C" void kernel_launch(void* const* d_in, const int* in_sizes, int n_in,
                              void* d_out, int out_size, void* d_ws, size_t ws_size,
                              hipStream_t stream) {
  const float* x = (const float*)d_in[0];
  const int* src = (const int*)d_in[1];
  const int* tgt = (const int*)d_in[2];
  const float* W_self = (const float*)d_in[3];
  const float* W_neigh = (const float*)d_in[4];
  const float* b_pack = (const float*)d_in[5];
  const float* w_score = (const float*)d_in[6];
  const float* b_score = (const float*)d_in[7];
  const float* W_u1 = (const float*)d_in[8];
  const float* b_u1 = (const float*)d_in[9];
  const float* W_u2 = (const float*)d_in[10];
  const float* b_u2 = (const float*)d_in[11];
  float* out = (float*)d_out;

  char* ws = (char*)d_ws;
  size_t off = 0;
  auto alloc = [&](size_t bytes) -> char* {
    char* p = ws + off;
    off += (bytes + 255) & ~(size_t)255;
    return p;
  };
  int* cnt = (int*)alloc((size_t)NN * 4);
  int* offsets = (int*)alloc((size_t)(NN + 1) * 4);
  int* cursor = (int*)alloc((size_t)NN * 4);
  int* csr = (int*)alloc((size_t)NE * 4);
  float* score = (float*)alloc((size_t)NN * 4);
  float* sel = (float*)alloc((size_t)NN * 4);
  int* bsum = (int*)alloc(512 * 4);
  unsigned* hist = (unsigned*)alloc(256 * 4);
  unsigned* state = (unsigned*)alloc(64);
  float* aggF = (float*)alloc((size_t)NN * FF * 4);  // 51.2 MB, reused after gemm0:
  unsigned* zdbf = (unsigned*)aggF;                   //   first half: z-bf16 then d-bf16
  unsigned* aggBF = (unsigned*)(aggF + (size_t)NN * (FF / 2));  // second half: bf16 agg out
  float* bufB = out;  // h, then d, live in d_out (element-wise in-place safe)

  hipMemsetAsync(cnt, 0, (size_t)NN * 4, stream);
  hipMemsetAsync(cursor, 0, (size_t)NN * 4, stream);
  hipMemsetAsync(hist, 0, 256 * 4, stream);
  k_init_state<<<1, 1, 0, stream>>>(state);

  // CSR by target
  k_degree<<<(NE + 255) / 256, 256, 0, stream>>>(tgt, cnt);
  k_blocksum<<<NB, 256, 0, stream>>>(cnt, bsum);
  k_scan_bsum<<<1, 512, 0, stream>>>(bsum);
  k_scan_final<<<NB, 256, 0, stream>>>(cnt, bsum, offsets);
  k_fill<<<(NE + 255) / 256, 256, 0, stream>>>(src, tgt, offsets, cursor, csr);

  // ---- compress (all f32: score path is selection-critical) ----
  k_agg<<<NN / 4, 256, 0, stream>>>(x, csr, offsets, aggF);
  k_gemm<0, true, false><<<NN / 8, 256, 0, stream>>>(aggF, W_neigh, x, W_self, b_pack,
                                                     nullptr, nullptr, nullptr, bufB, nullptr);
  k_score<<<NN / 4, 256, 0, stream>>>(bufB, w_score, b_score, score);

  // exact top-K (radix select, no host sync)
  for (int r = 0; r < 8; ++r) {
    k_hist<<<NB, 256, 0, stream>>>(score, state, hist, 8 * r);
    k_select_round<<<1, 256, 0, stream>>>(state, hist, 8 * r);
  }
  k_mask<<<NB, 256, 0, stream>>>(score, state, sel);

  // ---- decompress (bf16 gathers; selected rows stay f32) ----
  // diffusion 1: zg rows written only where selected; gated agg skips others
  k_gate_zg<<<NN / 4, 256, 0, stream>>>(bufB, score, sel, zdbf);
  k_agg_bf<true><<<NN / 4, 256, 0, stream>>>(zdbf, csr, offsets, sel, aggBF);
  k_gemm<1, false, true><<<NN / 8, 256, 0, stream>>>(aggBF, W_u1, nullptr, nullptr, b_u1,
                                                     bufB, score, sel, bufB,
                                                     (unsigned short*)zdbf);
  // diffusion 2: gather bf16(d), epilogue passthrough from f32 d
  k_agg_bf<false><<<NN / 4, 256, 0, stream>>>(zdbf, csr, offsets, nullptr, aggBF);
  k_gemm<2, false, true><<<NN / 8, 256, 0, stream>>>(aggBF, W_u2, nullptr, nullptr, b_u2,
                                                     bufB, nullptr, sel, out, nullptr);
}